// Round 2
// baseline (373.279 us; speedup 1.0000x reference)
//
#include <hip/hip_runtime.h>
#include <hip/hip_bf16.h>

#define NN 50000
#define NE 625000
#define DIM 128

// ---------------- precompute: C = L@W  (C[o][g] = sum_f L[o][f] * W[f][g]),
//                  cb[o] = sum_f L[o][f] * msg_b[f]
__global__ void prep_kernel(const float* __restrict__ L, const float* __restrict__ W,
                            const float* __restrict__ mb, float* __restrict__ C,
                            float* __restrict__ cb) {
    int idx = blockIdx.x * 256 + threadIdx.x;
    if (idx < DIM * DIM) {
        int o = idx >> 7, g = idx & 127;
        float s = 0.f;
        for (int f = 0; f < DIM; f++) s += L[o * DIM + f] * W[f * DIM + g];
        C[idx] = s;
    } else if (idx < DIM * DIM + DIM) {
        int o = idx - DIM * DIM;
        float s = 0.f;
        for (int f = 0; f < DIM; f++) s += L[o * DIM + f] * mb[f];
        cb[o] = s;
    }
}

// ---------------- histogram of src (edge_index delivered as int32 per harness)
__global__ void hist_kernel(const int* __restrict__ ei, int* __restrict__ deg) {
    int e = blockIdx.x * 256 + threadIdx.x;
    if (e < NE) atomicAdd(&deg[ei[e]], 1);
}

// ---------------- single-block exclusive scan over deg -> offs, cursor
__global__ void scan_kernel(const int* __restrict__ deg, int* __restrict__ offs,
                            int* __restrict__ cursor) {
    __shared__ int s[1024];
    int t = threadIdx.x;
    const int CH = 49;  // 1024*49 = 50176 >= 50000
    int base = t * CH;
    int sum = 0;
    for (int i = 0; i < CH; i++) {
        int idx = base + i;
        if (idx < NN) sum += deg[idx];
    }
    s[t] = sum;
    __syncthreads();
    for (int off = 1; off < 1024; off <<= 1) {
        int v = (t >= off) ? s[t - off] : 0;
        __syncthreads();
        s[t] += v;
        __syncthreads();
    }
    int run = (t > 0) ? s[t - 1] : 0;
    for (int i = 0; i < CH; i++) {
        int idx = base + i;
        if (idx < NN) {
            offs[idx] = run;
            cursor[idx] = run;
            run += deg[idx];
        }
    }
}

// ---------------- bin placement: sorted_dst grouped by src
__global__ void place_kernel(const int* __restrict__ ei, int* __restrict__ cursor,
                             int* __restrict__ sdst) {
    int e = blockIdx.x * 256 + threadIdx.x;
    if (e < NE) {
        int s = ei[e];
        int d = ei[NE + e];
        int pos = atomicAdd(&cursor[s], 1);
        sdst[pos] = d;
    }
}

// ---------------- gather-aggregate: one wave per node, P[n] = sum X[dst]
__global__ __launch_bounds__(256) void gather_kernel(const float* __restrict__ X,
                                                     const int* __restrict__ offs,
                                                     const int* __restrict__ deg,
                                                     const int* __restrict__ sdst,
                                                     float* __restrict__ agg) {
    int wave = (blockIdx.x * 256 + threadIdx.x) >> 6;
    int lane = threadIdx.x & 63;
    if (wave >= NN) return;
    int start = offs[wave];
    int cnt = deg[wave];
    const float2* Xp = (const float2*)X;
    float2 acc = make_float2(0.f, 0.f);
    int j = 0;
    for (; j + 4 <= cnt; j += 4) {
        int d0 = sdst[start + j + 0];
        int d1 = sdst[start + j + 1];
        int d2 = sdst[start + j + 2];
        int d3 = sdst[start + j + 3];
        float2 v0 = Xp[d0 * 64 + lane];
        float2 v1 = Xp[d1 * 64 + lane];
        float2 v2 = Xp[d2 * 64 + lane];
        float2 v3 = Xp[d3 * 64 + lane];
        acc.x += v0.x + v1.x + v2.x + v3.x;
        acc.y += v0.y + v1.y + v2.y + v3.y;
    }
    for (; j < cnt; j++) {
        int d = sdst[start + j];
        float2 v = Xp[d * 64 + lane];
        acc.x += v.x;
        acc.y += v.y;
    }
    ((float2*)agg)[wave * 64 + lane] = acc;
}

// ---------------- fused output GEMM:
// out[n][o] = relu( sum_k Acat[n][k]*Bcat[o][k] + deg[n]*cb[o] + lin_b[o] )
// Acat = [(1+eps)*X | agg] (K=256), Bcat = [L | C]
// NOTE: agg aliases out (row-disjoint per block; all agg reads drain before
// epilogue stores via the last __syncthreads) — no __restrict__ on these two.
#define TM 32
__global__ __launch_bounds__(256) void outgemm_kernel(
    const float* __restrict__ X, const float* agg, const int* __restrict__ deg,
    const float* __restrict__ L, const float* __restrict__ C, const float* __restrict__ cb,
    const float* __restrict__ lin_b, const float* __restrict__ epsp, float* out) {
    __shared__ float As[64][36];   // [k][r], padded
    __shared__ float Bs[64][132];  // [k][o], padded
    int tid = threadIdx.x;
    int tx = tid & 31;   // col group: cols 4*tx..4*tx+3
    int ty = tid >> 5;   // row group: rows 4*ty..4*ty+3
    int row0 = blockIdx.x * TM;
    float scale = 1.0f + *epsp;
    float acc[4][4] = {};

    for (int kc = 0; kc < 4; kc++) {
        int kbase = kc * 64;
        // stage A: 32 rows x 64 k, transposed, scaled
        {
            const float* src = (kbase < DIM) ? X : agg;
            float sc = (kbase < DIM) ? scale : 1.0f;
            int koff = kbase & 127;
            int r = tid & 31;
            int k0 = (tid >> 5) * 8;
            int row = row0 + r;
            if (row >= NN) row = NN - 1;
            const float* p = src + (size_t)row * DIM + koff + k0;
            float4 v0 = *(const float4*)p;
            float4 v1 = *(const float4*)(p + 4);
            As[k0 + 0][r] = v0.x * sc;
            As[k0 + 1][r] = v0.y * sc;
            As[k0 + 2][r] = v0.z * sc;
            As[k0 + 3][r] = v0.w * sc;
            As[k0 + 4][r] = v1.x * sc;
            As[k0 + 5][r] = v1.y * sc;
            As[k0 + 6][r] = v1.z * sc;
            As[k0 + 7][r] = v1.w * sc;
        }
        // stage B: 128 o x 64 k, transposed
        {
            const float* bsrc = (kbase < DIM) ? L : C;
            int koff = kbase & 127;
            int o = tid & 127;
            int k0 = (tid >> 7) * 32;
            const float* p = bsrc + o * DIM + koff + k0;
            for (int j = 0; j < 32; j += 4) {
                float4 v = *(const float4*)(p + j);
                Bs[k0 + j + 0][o] = v.x;
                Bs[k0 + j + 1][o] = v.y;
                Bs[k0 + j + 2][o] = v.z;
                Bs[k0 + j + 3][o] = v.w;
            }
        }
        __syncthreads();
#pragma unroll 8
        for (int k = 0; k < 64; k++) {
            float4 a = *(const float4*)&As[k][ty * 4];
            float4 b = *(const float4*)&Bs[k][tx * 4];
            acc[0][0] += a.x * b.x; acc[0][1] += a.x * b.y; acc[0][2] += a.x * b.z; acc[0][3] += a.x * b.w;
            acc[1][0] += a.y * b.x; acc[1][1] += a.y * b.y; acc[1][2] += a.y * b.z; acc[1][3] += a.y * b.w;
            acc[2][0] += a.z * b.x; acc[2][1] += a.z * b.y; acc[2][2] += a.z * b.z; acc[2][3] += a.z * b.w;
            acc[3][0] += a.w * b.x; acc[3][1] += a.w * b.y; acc[3][2] += a.w * b.z; acc[3][3] += a.w * b.w;
        }
        __syncthreads();
    }

    int o0 = tx * 4;
    float4 cbv = *(const float4*)(cb + o0);
    float4 lbv = *(const float4*)(lin_b + o0);
#pragma unroll
    for (int i = 0; i < 4; i++) {
        int row = row0 + ty * 4 + i;
        if (row >= NN) continue;
        float dg = (float)deg[row];
        float4 r;
        r.x = fmaxf(acc[i][0] + dg * cbv.x + lbv.x, 0.f);
        r.y = fmaxf(acc[i][1] + dg * cbv.y + lbv.y, 0.f);
        r.z = fmaxf(acc[i][2] + dg * cbv.z + lbv.z, 0.f);
        r.w = fmaxf(acc[i][3] + dg * cbv.w + lbv.w, 0.f);
        *(float4*)(out + (size_t)row * DIM + o0) = r;
    }
}

extern "C" void kernel_launch(void* const* d_in, const int* in_sizes, int n_in,
                              void* d_out, int out_size, void* d_ws, size_t ws_size,
                              hipStream_t stream) {
    const float* X = (const float*)d_in[0];
    const int* ei = (const int*)d_in[1];
    const float* epsp = (const float*)d_in[2];
    const float* msg_w = (const float*)d_in[3];
    const float* msg_b = (const float*)d_in[4];
    const float* lin_w = (const float*)d_in[5];
    const float* lin_b = (const float*)d_in[6];
    float* out = (float*)d_out;

    // agg lives in d_out (NN*DIM floats) — gather writes it, outgemm consumes
    // it in-place (row-disjoint per block).
    float* agg = out;

    // workspace layout (small arrays only, ~3.1 MB)
    int* deg = (int*)d_ws;        // NN ints
    int* offs = deg + NN;         // NN ints
    int* cursor = offs + NN;      // NN ints
    int* sdst = cursor + NN;      // NE ints
    float* C = (float*)(sdst + NE);  // DIM*DIM floats
    float* cb = C + DIM * DIM;       // DIM floats

    hipMemsetAsync(deg, 0, NN * sizeof(int), stream);

    prep_kernel<<<(DIM * DIM + DIM + 255) / 256, 256, 0, stream>>>(lin_w, msg_w, msg_b, C, cb);
    hist_kernel<<<(NE + 255) / 256, 256, 0, stream>>>(ei, deg);
    scan_kernel<<<1, 1024, 0, stream>>>(deg, offs, cursor);
    place_kernel<<<(NE + 255) / 256, 256, 0, stream>>>(ei, cursor, sdst);
    gather_kernel<<<(NN * 64 + 255) / 256, 256, 0, stream>>>(X, offs, deg, sdst, agg);
    outgemm_kernel<<<(NN + TM - 1) / TM, 256, 0, stream>>>(X, agg, deg, lin_w, C, cb, lin_b,
                                                           epsp, out);
}

// Round 3
// 260.556 us; speedup vs baseline: 1.4326x; 1.4326x over previous
//
#include <hip/hip_runtime.h>
#include <hip/hip_bf16.h>

#define NN 50000
#define NE 625000
#define DIM 128
#define SCAN_NB 196  // ceil(50000/256)

// ---------------- precompute: C = L@W  (C[o][g] = sum_f L[o][f] * W[f][g]),
//                  cb[o] = sum_f L[o][f] * msg_b[f]
__global__ void prep_kernel(const float* __restrict__ L, const float* __restrict__ W,
                            const float* __restrict__ mb, float* __restrict__ C,
                            float* __restrict__ cb) {
    int idx = blockIdx.x * 256 + threadIdx.x;
    if (idx < DIM * DIM) {
        int o = idx >> 7, g = idx & 127;
        float s = 0.f;
        for (int f = 0; f < DIM; f++) s += L[o * DIM + f] * W[f * DIM + g];
        C[idx] = s;
    } else if (idx < DIM * DIM + DIM) {
        int o = idx - DIM * DIM;
        float s = 0.f;
        for (int f = 0; f < DIM; f++) s += L[o * DIM + f] * mb[f];
        cb[o] = s;
    }
}

// ---------------- histogram of src (edge_index delivered as int32 per harness)
__global__ void hist_kernel(const int* __restrict__ ei, int* __restrict__ deg) {
    int e = blockIdx.x * 256 + threadIdx.x;
    if (e < NE) atomicAdd(&deg[e < NE ? ei[e] : 0], 1);
}

// ---------------- hierarchical scan, level 1: per-block sums of deg
__global__ __launch_bounds__(256) void scan_blocksum(const int* __restrict__ deg,
                                                     int* __restrict__ bsum) {
    __shared__ int s[256];
    int t = threadIdx.x;
    int idx = blockIdx.x * 256 + t;
    int v = (idx < NN) ? deg[idx] : 0;
    s[t] = v;
    __syncthreads();
    for (int off = 128; off > 0; off >>= 1) {
        if (t < off) s[t] += s[t + off];
        __syncthreads();
    }
    if (t == 0) bsum[blockIdx.x] = s[0];
}

// ---------------- level 2: exclusive scan of 196 block sums (one tiny block)
__global__ __launch_bounds__(256) void scan_level2(const int* __restrict__ bsum,
                                                   int* __restrict__ bbase) {
    __shared__ int s[256];
    int t = threadIdx.x;
    int v = (t < SCAN_NB) ? bsum[t] : 0;
    s[t] = v;
    __syncthreads();
    for (int off = 1; off < 256; off <<= 1) {
        int u = (t >= off) ? s[t - off] : 0;
        __syncthreads();
        s[t] += u;
        __syncthreads();
    }
    if (t < SCAN_NB) bbase[t] = s[t] - v;  // exclusive
}

// ---------------- level 3: intra-block exclusive scan + base -> offs, cursor
__global__ __launch_bounds__(256) void scan_final(const int* __restrict__ deg,
                                                  const int* __restrict__ bbase,
                                                  int* __restrict__ offs,
                                                  int* __restrict__ cursor) {
    __shared__ int s[256];
    int t = threadIdx.x;
    int idx = blockIdx.x * 256 + t;
    int v = (idx < NN) ? deg[idx] : 0;
    s[t] = v;
    __syncthreads();
    for (int off = 1; off < 256; off <<= 1) {
        int u = (t >= off) ? s[t - off] : 0;
        __syncthreads();
        s[t] += u;
        __syncthreads();
    }
    if (idx < NN) {
        int ex = bbase[blockIdx.x] + s[t] - v;
        offs[idx] = ex;
        cursor[idx] = ex;
    }
}

// ---------------- bin placement: sorted_dst grouped by src
__global__ void place_kernel(const int* __restrict__ ei, int* __restrict__ cursor,
                             int* __restrict__ sdst) {
    int e = blockIdx.x * 256 + threadIdx.x;
    if (e < NE) {
        int s = ei[e];
        int d = ei[NE + e];
        int pos = atomicAdd(&cursor[s], 1);
        sdst[pos] = d;
    }
}

// ---------------- gather-aggregate: one wave per node, P[n] = sum X[dst]
__global__ __launch_bounds__(256) void gather_kernel(const float* __restrict__ X,
                                                     const int* __restrict__ offs,
                                                     const int* __restrict__ deg,
                                                     const int* __restrict__ sdst,
                                                     float* __restrict__ agg) {
    int wave = (blockIdx.x * 256 + threadIdx.x) >> 6;
    int lane = threadIdx.x & 63;
    if (wave >= NN) return;
    int start = offs[wave];
    int cnt = deg[wave];
    const float2* Xp = (const float2*)X;
    float2 acc = make_float2(0.f, 0.f);
    int j = 0;
    for (; j + 4 <= cnt; j += 4) {
        int d0 = sdst[start + j + 0];
        int d1 = sdst[start + j + 1];
        int d2 = sdst[start + j + 2];
        int d3 = sdst[start + j + 3];
        float2 v0 = Xp[d0 * 64 + lane];
        float2 v1 = Xp[d1 * 64 + lane];
        float2 v2 = Xp[d2 * 64 + lane];
        float2 v3 = Xp[d3 * 64 + lane];
        acc.x += v0.x + v1.x + v2.x + v3.x;
        acc.y += v0.y + v1.y + v2.y + v3.y;
    }
    for (; j < cnt; j++) {
        int d = sdst[start + j];
        float2 v = Xp[d * 64 + lane];
        acc.x += v.x;
        acc.y += v.y;
    }
    ((float2*)agg)[wave * 64 + lane] = acc;
}

// ---------------- fused output GEMM:
// out[n][o] = relu( sum_k Acat[n][k]*Bcat[o][k] + deg[n]*cb[o] + lin_b[o] )
// Acat = [(1+eps)*X | agg] (K=256), Bcat = [L | C]
// NOTE: agg aliases out (row-disjoint per block; all agg reads drain before
// epilogue stores via the last __syncthreads) — no __restrict__ on these two.
#define TM 32
__global__ __launch_bounds__(256) void outgemm_kernel(
    const float* __restrict__ X, const float* agg, const int* __restrict__ deg,
    const float* __restrict__ L, const float* __restrict__ C, const float* __restrict__ cb,
    const float* __restrict__ lin_b, const float* __restrict__ epsp, float* out) {
    __shared__ float As[64][36];   // [k][r], padded
    __shared__ float Bs[64][132];  // [k][o], padded
    int tid = threadIdx.x;
    int tx = tid & 31;   // col group: cols 4*tx..4*tx+3
    int ty = tid >> 5;   // row group: rows 4*ty..4*ty+3
    int row0 = blockIdx.x * TM;
    float scale = 1.0f + *epsp;
    float acc[4][4] = {};

    for (int kc = 0; kc < 4; kc++) {
        int kbase = kc * 64;
        // stage A: 32 rows x 64 k, transposed, scaled
        {
            const float* src = (kbase < DIM) ? X : agg;
            float sc = (kbase < DIM) ? scale : 1.0f;
            int koff = kbase & 127;
            int r = tid & 31;
            int k0 = (tid >> 5) * 8;
            int row = row0 + r;
            if (row >= NN) row = NN - 1;
            const float* p = src + (size_t)row * DIM + koff + k0;
            float4 v0 = *(const float4*)p;
            float4 v1 = *(const float4*)(p + 4);
            As[k0 + 0][r] = v0.x * sc;
            As[k0 + 1][r] = v0.y * sc;
            As[k0 + 2][r] = v0.z * sc;
            As[k0 + 3][r] = v0.w * sc;
            As[k0 + 4][r] = v1.x * sc;
            As[k0 + 5][r] = v1.y * sc;
            As[k0 + 6][r] = v1.z * sc;
            As[k0 + 7][r] = v1.w * sc;
        }
        // stage B: 128 o x 64 k, transposed
        {
            const float* bsrc = (kbase < DIM) ? L : C;
            int koff = kbase & 127;
            int o = tid & 127;
            int k0 = (tid >> 7) * 32;
            const float* p = bsrc + o * DIM + koff + k0;
            for (int j = 0; j < 32; j += 4) {
                float4 v = *(const float4*)(p + j);
                Bs[k0 + j + 0][o] = v.x;
                Bs[k0 + j + 1][o] = v.y;
                Bs[k0 + j + 2][o] = v.z;
                Bs[k0 + j + 3][o] = v.w;
            }
        }
        __syncthreads();
#pragma unroll 8
        for (int k = 0; k < 64; k++) {
            float4 a = *(const float4*)&As[k][ty * 4];
            float4 b = *(const float4*)&Bs[k][tx * 4];
            acc[0][0] += a.x * b.x; acc[0][1] += a.x * b.y; acc[0][2] += a.x * b.z; acc[0][3] += a.x * b.w;
            acc[1][0] += a.y * b.x; acc[1][1] += a.y * b.y; acc[1][2] += a.y * b.z; acc[1][3] += a.y * b.w;
            acc[2][0] += a.z * b.x; acc[2][1] += a.z * b.y; acc[2][2] += a.z * b.z; acc[2][3] += a.z * b.w;
            acc[3][0] += a.w * b.x; acc[3][1] += a.w * b.y; acc[3][2] += a.w * b.z; acc[3][3] += a.w * b.w;
        }
        __syncthreads();
    }

    int o0 = tx * 4;
    float4 cbv = *(const float4*)(cb + o0);
    float4 lbv = *(const float4*)(lin_b + o0);
#pragma unroll
    for (int i = 0; i < 4; i++) {
        int row = row0 + ty * 4 + i;
        if (row >= NN) continue;
        float dg = (float)deg[row];
        float4 r;
        r.x = fmaxf(acc[i][0] + dg * cbv.x + lbv.x, 0.f);
        r.y = fmaxf(acc[i][1] + dg * cbv.y + lbv.y, 0.f);
        r.z = fmaxf(acc[i][2] + dg * cbv.z + lbv.z, 0.f);
        r.w = fmaxf(acc[i][3] + dg * cbv.w + lbv.w, 0.f);
        *(float4*)(out + (size_t)row * DIM + o0) = r;
    }
}

extern "C" void kernel_launch(void* const* d_in, const int* in_sizes, int n_in,
                              void* d_out, int out_size, void* d_ws, size_t ws_size,
                              hipStream_t stream) {
    const float* X = (const float*)d_in[0];
    const int* ei = (const int*)d_in[1];
    const float* epsp = (const float*)d_in[2];
    const float* msg_w = (const float*)d_in[3];
    const float* msg_b = (const float*)d_in[4];
    const float* lin_w = (const float*)d_in[5];
    const float* lin_b = (const float*)d_in[6];
    float* out = (float*)d_out;

    // agg lives in d_out (NN*DIM floats) — gather writes it, outgemm consumes
    // it in-place (row-disjoint per block).
    float* agg = out;

    // workspace layout (small arrays only, ~3.1 MB)
    int* deg = (int*)d_ws;        // NN ints
    int* offs = deg + NN;         // NN ints
    int* cursor = offs + NN;      // NN ints
    int* sdst = cursor + NN;      // NE ints
    float* C = (float*)(sdst + NE);  // DIM*DIM floats
    float* cb = C + DIM * DIM;       // DIM floats
    int* bsum = (int*)(cb + DIM);    // SCAN_NB ints
    int* bbase = bsum + SCAN_NB;     // SCAN_NB ints

    hipMemsetAsync(deg, 0, NN * sizeof(int), stream);

    prep_kernel<<<(DIM * DIM + DIM + 255) / 256, 256, 0, stream>>>(lin_w, msg_w, msg_b, C, cb);
    hist_kernel<<<(NE + 255) / 256, 256, 0, stream>>>(ei, deg);
    scan_blocksum<<<SCAN_NB, 256, 0, stream>>>(deg, bsum);
    scan_level2<<<1, 256, 0, stream>>>(bsum, bbase);
    scan_final<<<SCAN_NB, 256, 0, stream>>>(deg, bbase, offs, cursor);
    place_kernel<<<(NE + 255) / 256, 256, 0, stream>>>(ei, cursor, sdst);
    gather_kernel<<<(NN * 64 + 255) / 256, 256, 0, stream>>>(X, offs, deg, sdst, agg);
    outgemm_kernel<<<(NN + TM - 1) / TM, 256, 0, stream>>>(X, agg, deg, lin_w, C, cb, lin_b,
                                                           epsp, out);
}

// Round 5
// 224.938 us; speedup vs baseline: 1.6595x; 1.1583x over previous
//
#include <hip/hip_runtime.h>
#include <hip/hip_bf16.h>

#define NN 50000
#define NE 625000
#define DIM 128
#define SCAN_NB 196  // ceil(50000/256)

using fragAB = __attribute__((ext_vector_type(8))) short;
using fragC  = __attribute__((ext_vector_type(4))) float;

__device__ __forceinline__ unsigned short f2bf(float f) {
    unsigned int u = __float_as_uint(f);
    unsigned int r = u + 0x7FFFu + ((u >> 16) & 1u);  // RNE
    return (unsigned short)(r >> 16);
}

// ---------------- precompute: C = L@W, cb = L@msg_b, and bf16 Bh = [L | C]
__global__ void prep_kernel(const float* __restrict__ L, const float* __restrict__ W,
                            const float* __restrict__ mb, float* __restrict__ cb,
                            unsigned short* __restrict__ Bh) {
    int idx = blockIdx.x * 256 + threadIdx.x;
    if (idx < DIM * DIM) {
        int o = idx >> 7, g = idx & 127;
        float s = 0.f;
        for (int f = 0; f < DIM; f++) s += L[o * DIM + f] * W[f * DIM + g];
        Bh[o * 256 + 128 + g] = f2bf(s);          // C part
        Bh[o * 256 + g] = f2bf(L[o * DIM + g]);   // L part
    } else if (idx < DIM * DIM + DIM) {
        int o = idx - DIM * DIM;
        float s = 0.f;
        for (int f = 0; f < DIM; f++) s += L[o * DIM + f] * mb[f];
        cb[o] = s;
    }
}

// ---------------- X (fp32) -> Ah[n][0:128] (bf16)
__global__ __launch_bounds__(256) void xcast_kernel(const float* __restrict__ X,
                                                    unsigned short* __restrict__ Ah) {
    int idx = (blockIdx.x * 256 + threadIdx.x) * 4;
    if (idx >= NN * DIM) return;
    int n = idx >> 7, k = idx & 127;
    float4 v = *(const float4*)(X + idx);
    uint2 p;
    p.x = (unsigned int)f2bf(v.x) | ((unsigned int)f2bf(v.y) << 16);
    p.y = (unsigned int)f2bf(v.z) | ((unsigned int)f2bf(v.w) << 16);
    *(uint2*)(Ah + (size_t)n * 256 + k) = p;
}

// ---------------- histogram of src
__global__ void hist_kernel(const int* __restrict__ ei, int* __restrict__ deg) {
    int e = blockIdx.x * 256 + threadIdx.x;
    if (e < NE) atomicAdd(&deg[ei[e]], 1);
}

// ---------------- hierarchical scan
__global__ __launch_bounds__(256) void scan_blocksum(const int* __restrict__ deg,
                                                     int* __restrict__ bsum) {
    __shared__ int s[256];
    int t = threadIdx.x;
    int idx = blockIdx.x * 256 + t;
    s[t] = (idx < NN) ? deg[idx] : 0;
    __syncthreads();
    for (int off = 128; off > 0; off >>= 1) {
        if (t < off) s[t] += s[t + off];
        __syncthreads();
    }
    if (t == 0) bsum[blockIdx.x] = s[0];
}

__global__ __launch_bounds__(256) void scan_level2(const int* __restrict__ bsum,
                                                   int* __restrict__ bbase) {
    __shared__ int s[256];
    int t = threadIdx.x;
    int v = (t < SCAN_NB) ? bsum[t] : 0;
    s[t] = v;
    __syncthreads();
    for (int off = 1; off < 256; off <<= 1) {
        int u = (t >= off) ? s[t - off] : 0;
        __syncthreads();
        s[t] += u;
        __syncthreads();
    }
    if (t < SCAN_NB) bbase[t] = s[t] - v;  // exclusive
}

__global__ __launch_bounds__(256) void scan_final(const int* __restrict__ deg,
                                                  const int* __restrict__ bbase,
                                                  int* __restrict__ offs,
                                                  int* __restrict__ cursor) {
    __shared__ int s[256];
    int t = threadIdx.x;
    int idx = blockIdx.x * 256 + t;
    int v = (idx < NN) ? deg[idx] : 0;
    s[t] = v;
    __syncthreads();
    for (int off = 1; off < 256; off <<= 1) {
        int u = (t >= off) ? s[t - off] : 0;
        __syncthreads();
        s[t] += u;
        __syncthreads();
    }
    if (idx < NN) {
        int ex = bbase[blockIdx.x] + s[t] - v;
        offs[idx] = ex;
        cursor[idx] = ex;
    }
}

// ---------------- bin placement
__global__ void place_kernel(const int* __restrict__ ei, int* __restrict__ cursor,
                             int* __restrict__ sdst) {
    int e = blockIdx.x * 256 + threadIdx.x;
    if (e < NE) {
        int s = ei[e];
        int d = ei[NE + e];
        int pos = atomicAdd(&cursor[s], 1);
        sdst[pos] = d;
    }
}

// ---------------- gather: one wave per node; reads bf16 X rows (Ah[:,0:128]),
// accumulates fp32, writes bf16 agg into Ah[:,128:256].
__global__ __launch_bounds__(256) void gather_kernel(const int* __restrict__ offs,
                                                     const int* __restrict__ deg,
                                                     const int* __restrict__ sdst,
                                                     unsigned short* Ah) {
    int wave = (blockIdx.x * 256 + threadIdx.x) >> 6;
    int lane = threadIdx.x & 63;
    if (wave >= NN) return;
    int start = offs[wave];
    int cnt = deg[wave];
    float ax = 0.f, ay = 0.f;
    int j = 0;
    for (; j + 4 <= cnt; j += 4) {
        int d0 = sdst[start + j + 0];
        int d1 = sdst[start + j + 1];
        int d2 = sdst[start + j + 2];
        int d3 = sdst[start + j + 3];
        unsigned int v0 = *(const unsigned int*)(Ah + (size_t)d0 * 256 + lane * 2);
        unsigned int v1 = *(const unsigned int*)(Ah + (size_t)d1 * 256 + lane * 2);
        unsigned int v2 = *(const unsigned int*)(Ah + (size_t)d2 * 256 + lane * 2);
        unsigned int v3 = *(const unsigned int*)(Ah + (size_t)d3 * 256 + lane * 2);
        ax += __uint_as_float(v0 << 16) + __uint_as_float(v1 << 16) +
              __uint_as_float(v2 << 16) + __uint_as_float(v3 << 16);
        ay += __uint_as_float(v0 & 0xffff0000u) + __uint_as_float(v1 & 0xffff0000u) +
              __uint_as_float(v2 & 0xffff0000u) + __uint_as_float(v3 & 0xffff0000u);
    }
    for (; j < cnt; j++) {
        int d = sdst[start + j];
        unsigned int v = *(const unsigned int*)(Ah + (size_t)d * 256 + lane * 2);
        ax += __uint_as_float(v << 16);
        ay += __uint_as_float(v & 0xffff0000u);
    }
    unsigned int packed = (unsigned int)f2bf(ax) | ((unsigned int)f2bf(ay) << 16);
    *(unsigned int*)(Ah + (size_t)wave * 256 + 128 + lane * 2) = packed;
}

// ---------------- MFMA output GEMM:
// out[n][o] = relu( sum_k Ahat[n][k]*Bhat[o][k] + deg[n]*cb[o] + lin_b[o] )
// Ahat = bf16 [X | agg] (K=256), Bhat = bf16 [scale*L | C] (scale applied
// during B staging). Ah aliases out: each block reads only its own 128 rows
// during the K loop and overwrites them only in the epilogue (after the last
// barrier); cross-block byte ranges are disjoint.
// 128x128 tile, 4 waves x (64x64), 16x16x32 bf16 MFMA.
__global__ __launch_bounds__(256) void outgemm_kernel(
    const unsigned short* Ah, const unsigned short* __restrict__ Bh,
    const int* __restrict__ deg, const float* __restrict__ cb,
    const float* __restrict__ lin_b, const float* __restrict__ epsp, float* out) {
    __shared__ unsigned short As[128 * 40];  // [row][32 k + 8 pad]
    __shared__ unsigned short Bs[128 * 40];
    int tid = threadIdx.x;
    int lane = tid & 63;
    int wave = tid >> 6;
    int m16 = lane & 15;
    int quad = lane >> 4;
    int waveM = (wave & 1) * 64;
    int waveN = (wave >> 1) * 64;
    int r0 = blockIdx.x * 128;
    float scale = 1.0f + *epsp;

    fragC acc[4][4];
#pragma unroll
    for (int i = 0; i < 4; i++)
#pragma unroll
        for (int j = 0; j < 4; j++) acc[i][j] = (fragC){0.f, 0.f, 0.f, 0.f};

    int srow = tid >> 1;       // staging row (0..127)
    int shalf = tid & 1;       // which 16-element half of the 32-k slice
    int arow = r0 + srow;
    if (arow >= NN) arow = NN - 1;

    for (int kc = 0; kc < 8; kc++) {
        int kb = kc * 32;
        // stage A slice: 128 rows x 32 k bf16 = 8 KB; 256 thr x 32 B (2x uint4)
        {
            const uint4* gp = (const uint4*)(Ah + (size_t)arow * 256 + kb + shalf * 16);
            uint4 w0 = gp[0];   // elements [0..8) of this half
            uint4 w1 = gp[1];   // elements [8..16)
            uint4* lp = (uint4*)(As + srow * 40 + shalf * 16);
            lp[0] = w0;
            lp[1] = w1;
        }
        // stage B slice: 128 o x 32 k; scale the k<128 half by (1+eps)
        {
            const uint4* gp = (const uint4*)(Bh + (size_t)srow * 256 + kb + shalf * 16);
            uint4 w0 = gp[0];
            uint4 w1 = gp[1];
            if (kb < 128) {
                unsigned int* u0 = (unsigned int*)&w0;
                unsigned int* u1 = (unsigned int*)&w1;
#pragma unroll
                for (int q = 0; q < 4; q++) {
                    float lo = __uint_as_float(u0[q] << 16) * scale;
                    float hi = __uint_as_float(u0[q] & 0xffff0000u) * scale;
                    u0[q] = (unsigned int)f2bf(lo) | ((unsigned int)f2bf(hi) << 16);
                    lo = __uint_as_float(u1[q] << 16) * scale;
                    hi = __uint_as_float(u1[q] & 0xffff0000u) * scale;
                    u1[q] = (unsigned int)f2bf(lo) | ((unsigned int)f2bf(hi) << 16);
                }
            }
            uint4* lp = (uint4*)(Bs + srow * 40 + shalf * 16);
            lp[0] = w0;
            lp[1] = w1;
        }
        __syncthreads();

        fragAB a[4], b[4];
#pragma unroll
        for (int i = 0; i < 4; i++)
            a[i] = *(const fragAB*)(As + (waveM + i * 16 + m16) * 40 + quad * 8);
#pragma unroll
        for (int j = 0; j < 4; j++)
            b[j] = *(const fragAB*)(Bs + (waveN + j * 16 + m16) * 40 + quad * 8);
#pragma unroll
        for (int i = 0; i < 4; i++)
#pragma unroll
            for (int j = 0; j < 4; j++)
                acc[i][j] = __builtin_amdgcn_mfma_f32_16x16x32_bf16(a[i], b[j], acc[i][j], 0, 0, 0);
        __syncthreads();
    }

    // epilogue: D row = waveM + i*16 + quad*4 + r, col = waveN + j*16 + m16
#pragma unroll
    for (int j = 0; j < 4; j++) {
        int col = waveN + j * 16 + m16;
        float cbc = cb[col];
        float lbc = lin_b[col];
#pragma unroll
        for (int i = 0; i < 4; i++) {
            int rbase = r0 + waveM + i * 16 + quad * 4;
#pragma unroll
            for (int r = 0; r < 4; r++) {
                int row = rbase + r;
                if (row < NN) {
                    float dg = (float)deg[row];
                    float v = acc[i][j][r] + dg * cbc + lbc;
                    out[(size_t)row * 128 + col] = fmaxf(v, 0.f);
                }
            }
        }
    }
}

extern "C" void kernel_launch(void* const* d_in, const int* in_sizes, int n_in,
                              void* d_out, int out_size, void* d_ws, size_t ws_size,
                              hipStream_t stream) {
    const float* X = (const float*)d_in[0];
    const int* ei = (const int*)d_in[1];
    const float* epsp = (const float*)d_in[2];
    const float* msg_w = (const float*)d_in[3];
    const float* msg_b = (const float*)d_in[4];
    const float* lin_w = (const float*)d_in[5];
    const float* lin_b = (const float*)d_in[6];
    float* out = (float*)d_out;

    // Ah = [bf16 X | bf16 agg], 50000 x 256 bf16 = 25.6 MB, aliases d_out
    unsigned short* Ah = (unsigned short*)d_out;

    // workspace (~3.2 MB)
    int* deg = (int*)d_ws;            // NN
    int* offs = deg + NN;             // NN
    int* cursor = offs + NN;          // NN
    int* sdst = cursor + NN;          // NE
    int* bsum = sdst + NE;            // SCAN_NB
    int* bbase = bsum + SCAN_NB;      // SCAN_NB
    float* cb = (float*)(bbase + SCAN_NB);          // DIM floats
    unsigned short* Bh = (unsigned short*)(cb + DIM);  // 128*256 bf16

    hipMemsetAsync(deg, 0, NN * sizeof(int), stream);

    prep_kernel<<<(DIM * DIM + DIM + 255) / 256, 256, 0, stream>>>(lin_w, msg_w, msg_b, cb, Bh);
    xcast_kernel<<<(NN * DIM / 4 + 255) / 256, 256, 0, stream>>>(X, Ah);
    hist_kernel<<<(NE + 255) / 256, 256, 0, stream>>>(ei, deg);
    scan_blocksum<<<SCAN_NB, 256, 0, stream>>>(deg, bsum);
    scan_level2<<<1, 256, 0, stream>>>(bsum, bbase);
    scan_final<<<SCAN_NB, 256, 0, stream>>>(deg, bbase, offs, cursor);
    place_kernel<<<(NE + 255) / 256, 256, 0, stream>>>(ei, cursor, sdst);
    gather_kernel<<<(NN * 64 + 255) / 256, 256, 0, stream>>>(offs, deg, sdst, Ah);
    outgemm_kernel<<<(NN + 127) / 128, 256, 0, stream>>>(Ah, Bh, deg, cb, lin_b, epsp, out);
}